// Round 3
// baseline (1194.907 us; speedup 1.0000x reference)
//
#include <hip/hip_runtime.h>

#define DD 128
#define HH 160
#define WW 160
#define PLANE (DD * HH * WW)   // 3276800 voxels per channel

// One scaling-and-squaring step: fout = f + trilinear_sample(f, id + f*100),
// where f = fin * scale_in (scale_in is a power of two: exact, commutes with
// every rounding below, so fusing it is bit-equivalent to prescaling).
//
// All arithmetic uses explicit _rn intrinsics to forbid FMA contraction and
// reassociation so the op sequence bit-matches the numpy reference.
__global__ __launch_bounds__(256) void diffeo_step(const float* __restrict__ fin,
                                                   float* __restrict__ fout,
                                                   float scale_in) {
    int idx = blockIdx.x * blockDim.x + threadIdx.x;
    if (idx >= PLANE) return;

    int x = idx % WW;
    int y = (idx / WW) % HH;
    int z = idx / (WW * HH);

    float fx = __fmul_rn(fin[idx],             scale_in);
    float fy = __fmul_rn(fin[idx + PLANE],     scale_in);
    float fz = __fmul_rn(fin[idx + 2 * PLANE], scale_in);

    // grid = sample_grid + flow*100  (separate mul + add, NO fma)
    float px = __fadd_rn((float)x, __fmul_rn(fx, 100.0f));
    float py = __fadd_rn((float)y, __fmul_rn(fy, 100.0f));
    float pz = __fadd_rn((float)z, __fmul_rn(fz, 100.0f));

    // normalize: (p - ext/2) / ext * 2    (ext = [159, 159, 127])
    float gx = __fmul_rn(__fdiv_rn(__fsub_rn(px, 79.5f), 159.0f), 2.0f);
    float gy = __fmul_rn(__fdiv_rn(__fsub_rn(py, 79.5f), 159.0f), 2.0f);
    float gz = __fmul_rn(__fdiv_rn(__fsub_rn(pz, 63.5f), 127.0f), 2.0f);

    // denormalize: ((g + 1) * 0.5) * (N-1)   — left-associated like the ref
    float ix = __fmul_rn(__fmul_rn(__fadd_rn(gx, 1.0f), 0.5f), 159.0f);
    float iy = __fmul_rn(__fmul_rn(__fadd_rn(gy, 1.0f), 0.5f), 159.0f);
    float iz = __fmul_rn(__fmul_rn(__fadd_rn(gz, 1.0f), 0.5f), 127.0f);

    float x0f = floorf(ix), y0f = floorf(iy), z0f = floorf(iz);
    int x0 = (int)x0f, y0 = (int)y0f, z0 = (int)z0f;
    float wx1 = __fsub_rn(ix, x0f);
    float wy1 = __fsub_rn(iy, y0f);
    float wz1 = __fsub_rn(iz, z0f);
    float wx0 = __fsub_rn(1.0f, wx1);
    float wy0 = __fsub_rn(1.0f, wy1);
    float wz0 = __fsub_rn(1.0f, wz1);

    float sx = 0.0f, sy = 0.0f, sz = 0.0f;

    bool xin[2] = { (x0 >= 0) && (x0 < WW), (x0 + 1 >= 0) && (x0 + 1 < WW) };
    bool yin[2] = { (y0 >= 0) && (y0 < HH), (y0 + 1 >= 0) && (y0 + 1 < HH) };
    bool zin[2] = { (z0 >= 0) && (z0 < DD), (z0 + 1 >= 0) && (z0 + 1 < DD) };
    float wxa[2] = { wx0, wx1 };
    float wya[2] = { wy0, wy1 };
    float wza[2] = { wz0, wz1 };

    // Corner order matches the reference: z outer, y mid, x inner,
    // left-to-right summation.
#pragma unroll
    for (int dz = 0; dz < 2; ++dz) {
        int zi = z0 + dz;
#pragma unroll
        for (int dy = 0; dy < 2; ++dy) {
            int yi = y0 + dy;
#pragma unroll
            for (int dx = 0; dx < 2; ++dx) {
                int xi = x0 + dx;
                if (zin[dz] && yin[dy] && xin[dx]) {
                    float w = __fmul_rn(__fmul_rn(wza[dz], wya[dy]), wxa[dx]);
                    int off = (zi * HH + yi) * WW + xi;
                    sx = __fadd_rn(sx, __fmul_rn(fin[off],             w));
                    sy = __fadd_rn(sy, __fmul_rn(fin[off + PLANE],     w));
                    sz = __fadd_rn(sz, __fmul_rn(fin[off + 2 * PLANE], w));
                }
            }
        }
    }

    fout[idx]             = __fadd_rn(fx, __fmul_rn(sx, scale_in));
    fout[idx + PLANE]     = __fadd_rn(fy, __fmul_rn(sy, scale_in));
    fout[idx + 2 * PLANE] = __fadd_rn(fz, __fmul_rn(sz, scale_in));
}

extern "C" void kernel_launch(void* const* d_in, const int* in_sizes, int n_in,
                              void* d_out, int out_size, void* d_ws, size_t ws_size,
                              hipStream_t stream) {
    const float* velocity = (const float*)d_in[0];
    float* out = (float*)d_out;
    float* ws  = (float*)d_ws;

    const int threads = 256;
    const int blocks = (PLANE + threads - 1) / threads;

    // Step 1: velocity (exact 2^-7 prescale fused) -> out
    diffeo_step<<<blocks, threads, 0, stream>>>(velocity, out, 1.0f / 128.0f);

    // Steps 2..7 ping-pong WITHOUT aliasing; final step writes d_out.
    // it=1: out->ws, it=2: ws->out, it=3: out->ws, it=4: ws->out,
    // it=5: out->ws, it=6: ws->out  (7 steps total, result in d_out)
    const float* src = out;
    float* bufs[2] = { ws, out };
    for (int it = 1; it < 7; ++it) {
        float* dst = bufs[1 - (it & 1)];
        diffeo_step<<<blocks, threads, 0, stream>>>(src, dst, 1.0f);
        src = dst;
    }
}

// Round 4
// 480.589 us; speedup vs baseline: 2.4863x; 2.4863x over previous
//
#include <hip/hip_runtime.h>

#define DD 128
#define HH 160
#define WW 160
#define PLANE (DD * HH * WW)   // 3276800 voxels per channel

// ---------------------------------------------------------------------------
// Pack: channel-major velocity -> interleaved (xyz per voxel), prescaled by
// 2^-7 (exact power of two, commutes with all later roundings).
// ---------------------------------------------------------------------------
__global__ __launch_bounds__(256) void pack_kernel(const float* __restrict__ vel,
                                                   float* __restrict__ out) {
    int idx = blockIdx.x * blockDim.x + threadIdx.x;
    if (idx >= PLANE) return;
    const float s = 1.0f / 128.0f;
    float vx = __fmul_rn(vel[idx],             s);
    float vy = __fmul_rn(vel[idx + PLANE],     s);
    float vz = __fmul_rn(vel[idx + 2 * PLANE], s);
    float* p = out + idx * 3;
    p[0] = vx; p[1] = vy; p[2] = vz;
}

// ---------------------------------------------------------------------------
// One scaling-and-squaring step on INTERLEAVED flow:
//   fout = f + trilinear_sample(f, id + f*100)
// Branchless: all 8 corners loaded from clamped addresses; out-of-bounds
// corners get weight 0 (w*mask is exact). All fp ops use _rn intrinsics in
// the reference's exact order (chaotic iteration -> must bit-match numpy).
// DST_CM: write channel-major (final step into d_out).
// ---------------------------------------------------------------------------
template<bool DST_CM>
__global__ __launch_bounds__(256) void diffeo_step(const float* __restrict__ fin,
                                                   float* __restrict__ fout) {
    int idx = blockIdx.x * blockDim.x + threadIdx.x;
    if (idx >= PLANE) return;

    int x = idx % WW;
    int y = (idx / WW) % HH;
    int z = idx / (WW * HH);

    const float* self = fin + idx * 3;
    float fx = self[0];
    float fy = self[1];
    float fz = self[2];

    // grid = sample_grid + flow*100  (separate mul + add, NO fma)
    float px = __fadd_rn((float)x, __fmul_rn(fx, 100.0f));
    float py = __fadd_rn((float)y, __fmul_rn(fy, 100.0f));
    float pz = __fadd_rn((float)z, __fmul_rn(fz, 100.0f));

    // normalize: (p - ext/2) / ext * 2   (ext = [159, 159, 127])
    float gx = __fmul_rn(__fdiv_rn(__fsub_rn(px, 79.5f), 159.0f), 2.0f);
    float gy = __fmul_rn(__fdiv_rn(__fsub_rn(py, 79.5f), 159.0f), 2.0f);
    float gz = __fmul_rn(__fdiv_rn(__fsub_rn(pz, 63.5f), 127.0f), 2.0f);

    // denormalize: ((g + 1) * 0.5) * (N-1)  — left-associated like the ref
    float ix = __fmul_rn(__fmul_rn(__fadd_rn(gx, 1.0f), 0.5f), 159.0f);
    float iy = __fmul_rn(__fmul_rn(__fadd_rn(gy, 1.0f), 0.5f), 159.0f);
    float iz = __fmul_rn(__fmul_rn(__fadd_rn(gz, 1.0f), 0.5f), 127.0f);

    float x0f = floorf(ix), y0f = floorf(iy), z0f = floorf(iz);
    int x0 = (int)x0f, y0 = (int)y0f, z0 = (int)z0f;
    float wx1 = __fsub_rn(ix, x0f);
    float wy1 = __fsub_rn(iy, y0f);
    float wz1 = __fsub_rn(iz, z0f);
    float wxa[2] = { __fsub_rn(1.0f, wx1), wx1 };
    float wya[2] = { __fsub_rn(1.0f, wy1), wy1 };
    float wza[2] = { __fsub_rn(1.0f, wz1), wz1 };

    // clamped indices + in-bounds flags per axis
    int xc[2], yc[2], zc[2];
    bool xin[2], yin[2], zin[2];
#pragma unroll
    for (int d = 0; d < 2; ++d) {
        int xv = x0 + d, yv = y0 + d, zv = z0 + d;
        xin[d] = (xv >= 0) && (xv < WW);
        yin[d] = (yv >= 0) && (yv < HH);
        zin[d] = (zv >= 0) && (zv < DD);
        xc[d] = min(max(xv, 0), WW - 1);
        yc[d] = min(max(yv, 0), HH - 1);
        zc[d] = min(max(zv, 0), DD - 1);
    }

    // Load all 8 corners unconditionally (clamped addresses), then accumulate
    // in the reference's corner order (z outer, y mid, x inner).
    float cvx[8], cvy[8], cvz[8], cw[8];
#pragma unroll
    for (int dz = 0; dz < 2; ++dz) {
#pragma unroll
        for (int dy = 0; dy < 2; ++dy) {
#pragma unroll
            for (int dx = 0; dx < 2; ++dx) {
                int c = dz * 4 + dy * 2 + dx;
                int off3 = ((zc[dz] * HH + yc[dy]) * WW + xc[dx]) * 3;
                const float* p = fin + off3;
                cvx[c] = p[0];
                cvy[c] = p[1];
                cvz[c] = p[2];
                float w = __fmul_rn(__fmul_rn(wza[dz], wya[dy]), wxa[dx]);
                cw[c] = (zin[dz] && yin[dy] && xin[dx]) ? w : 0.0f;  // w*mask, exact
            }
        }
    }

    float sx = 0.0f, sy = 0.0f, sz = 0.0f;
#pragma unroll
    for (int c = 0; c < 8; ++c) {
        sx = __fadd_rn(sx, __fmul_rn(cvx[c], cw[c]));
        sy = __fadd_rn(sy, __fmul_rn(cvy[c], cw[c]));
        sz = __fadd_rn(sz, __fmul_rn(cvz[c], cw[c]));
    }

    float ox = __fadd_rn(fx, sx);
    float oy = __fadd_rn(fy, sy);
    float oz = __fadd_rn(fz, sz);

    if (DST_CM) {
        fout[idx]             = ox;
        fout[idx + PLANE]     = oy;
        fout[idx + 2 * PLANE] = oz;
    } else {
        float* p = fout + idx * 3;
        p[0] = ox; p[1] = oy; p[2] = oz;
    }
}

extern "C" void kernel_launch(void* const* d_in, const int* in_sizes, int n_in,
                              void* d_out, int out_size, void* d_ws, size_t ws_size,
                              hipStream_t stream) {
    const float* velocity = (const float*)d_in[0];
    float* A = (float*)d_out;  // reused as interleaved scratch until final step
    float* B = (float*)d_ws;   // interleaved scratch (3*PLANE floats)

    const int threads = 256;
    const int blocks = (PLANE + threads - 1) / threads;

    // pack: velocity (chan-major, x 2^-7) -> B interleaved
    pack_kernel<<<blocks, threads, 0, stream>>>(velocity, B);

    // 7 steps, ping-pong; final step reads B, writes d_out channel-major.
    // s1: B->A, s2: A->B, s3: B->A, s4: A->B, s5: B->A, s6: A->B, s7: B->A(CM)
    diffeo_step<false><<<blocks, threads, 0, stream>>>(B, A);  // s1
    diffeo_step<false><<<blocks, threads, 0, stream>>>(A, B);  // s2
    diffeo_step<false><<<blocks, threads, 0, stream>>>(B, A);  // s3
    diffeo_step<false><<<blocks, threads, 0, stream>>>(A, B);  // s4
    diffeo_step<false><<<blocks, threads, 0, stream>>>(B, A);  // s5
    diffeo_step<false><<<blocks, threads, 0, stream>>>(A, B);  // s6
    diffeo_step<true ><<<blocks, threads, 0, stream>>>(B, A);  // s7 -> d_out CM
}